// Round 1
// 121.932 us; speedup vs baseline: 1.0598x; 1.0598x over previous
//
#include <hip/hip_runtime.h>

#define BHH 32      // B*H
#define SEQ 2048
#define DH 64
#define BQ 64       // Q rows per block (16 per wave, 4 waves)
#define BK 64       // K/V rows per tile
#define NKT (SEQ / BK)   // 32
#define NQB (SEQ / BQ)   // 32
#define NT  (BHH * NKT)  // 1024 (bh,kt) tiles

typedef __attribute__((ext_vector_type(8))) _Float16 half8_t;
typedef __attribute__((ext_vector_type(4))) _Float16 half4_t;
typedef __attribute__((ext_vector_type(2))) _Float16 half2_t;
typedef __attribute__((ext_vector_type(4))) float f32x4;

__device__ __forceinline__ void async_copy16(const void* g, const void* lds) {
    __builtin_amdgcn_global_load_lds(
        (const __attribute__((address_space(1))) unsigned int*)g,
        (__attribute__((address_space(3))) unsigned int*)lds, 16, 0, 0);
}

__device__ __forceinline__ half2_t pkrtz(float a, float b) {
    return __builtin_bit_cast(half2_t, __builtin_amdgcn_cvt_pkrtz(a, b));
}

// ---------------------------------------------------------------------------
// Fused prep: blocks [0,NT) convert K, [NT,2NT) convert V. One (bh,kt) 64x64
// fp32 tile per block, coalesced loads, LDS transpose, f16 fragment stores.
//   Kf frag bid=c*2+k0: lane L holds K[16c+(L&15)][32k0+8(L>>4)+j]  (QK^T A-op)
//   Vf frag f=cn*2+k1:  lane L, elem j holds
//       V[32k1 + 16*(j>=4) + 4*(L>>4) + (j&3)][16cn+(L&15)]
//   i.e. the 16x16x32 A-operand with k-permutation sigma(q8j) =
//   (j>=4)*16 + quad*4 + (j&3) baked in, so the PV B-operand is just the
//   concatenation of the two 4-wide P fragments the softmax already holds.
// ---------------------------------------------------------------------------
__global__ __launch_bounds__(256) void prep_kv(const float* __restrict__ K,
                                               const float* __restrict__ V,
                                               _Float16* __restrict__ Kf,
                                               _Float16* __restrict__ Vf) {
    __shared__ _Float16 l[64 * 76];
    const int t = threadIdx.x;
    const int wave = t >> 6, lane = t & 63, ln15 = lane & 15, quad = lane >> 4;
    const int row = t >> 2, col0 = (t & 3) * 16;
    int b = blockIdx.x;

    if (b < NT) {                                    // ---- K path ----
        const float4* src = (const float4*)(K + (size_t)b * 4096 + row * 64 + col0);
        #pragma unroll
        for (int q = 0; q < 2; ++q) {
            float4 f0 = src[q * 2], f1 = src[q * 2 + 1];
            half8_t w = { (_Float16)f0.x, (_Float16)f0.y, (_Float16)f0.z, (_Float16)f0.w,
                          (_Float16)f1.x, (_Float16)f1.y, (_Float16)f1.z, (_Float16)f1.w };
            *(half8_t*)&l[row * 72 + col0 + q * 8] = w;
        }
        __syncthreads();
        #pragma unroll
        for (int p = 0; p < 2; ++p) {
            const int bid = wave * 2 + p, c = bid >> 1, k0 = bid & 1;
            half8_t w = *(const half8_t*)&l[(c * 16 + ln15) * 72 + k0 * 32 + quad * 8];
            *(half8_t*)&Kf[(size_t)b * 4096 + bid * 512 + lane * 8] = w;
        }
    } else {                                         // ---- V path ----
        b -= NT;
        const float4* src = (const float4*)(V + (size_t)b * 4096 + row * 64 + col0);
        #pragma unroll
        for (int q = 0; q < 4; ++q) {
            float4 f = src[q];
            half4_t w = { (_Float16)f.x, (_Float16)f.y, (_Float16)f.z, (_Float16)f.w };
            *(half4_t*)&l[row * 76 + col0 + q * 4] = w;
        }
        __syncthreads();
        #pragma unroll
        for (int p = 0; p < 2; ++p) {
            const int f = wave * 2 + p, cn = f >> 1, k1 = f & 1;
            half8_t w;
            #pragma unroll
            for (int jj = 0; jj < 8; ++jj) {
                const int krow = k1 * 32 + ((jj & 4) << 2) + quad * 4 + (jj & 3);
                w[jj] = l[krow * 76 + cn * 16 + ln15];
            }
            *(half8_t*)&Vf[(size_t)b * 4096 + f * 512 + lane * 8] = w;
        }
    }
}

// ---------------------------------------------------------------------------
// Flash attention: 256 threads = 4 waves; each wave owns 16 Q-rows.
// S^T = K(A) x Q(B) via 16x16x32 f16; softmax register-resident (1 row/lane,
// lane-partial denominator, cross-quad reduce deferred to epilogue);
// O^T += V^T(A) x P^T(B) via 16x16x32 f16 with permuted-k Vf layout.
// ---------------------------------------------------------------------------
__global__ __launch_bounds__(256, 4) void fattn_kernel(
        const float* __restrict__ Q, const _Float16* __restrict__ Kf,
        const _Float16* __restrict__ Vf, float* __restrict__ O) {
    const int bh = blockIdx.x & 31;
    const int r = blockIdx.x >> 5, j = r & 7, rnd = r >> 3;
    const int qb = (rnd == 0) ? 31 - j : (rnd == 1) ? 16 + j
                 : (rnd == 2) ? 15 - j : j;          // per-CU load balance
    const int tid  = threadIdx.x;
    const int wave = tid >> 6;
    const int lane = tid & 63;
    const int ln15 = lane & 15;
    const int quad = lane >> 4;

    __shared__ _Float16 ldsK[2][4096];               // dbuf 8 KB K-frags
    __shared__ _Float16 ldsV[2][4096];               // dbuf 8 KB V-frags

    const size_t base = (size_t)bh * SEQ * DH;
    const int q0   = qb * BQ;
    const int qrow = q0 + wave * 16;                 // wave's 16 Q-rows
    const size_t tb = (size_t)(bh * NKT) * 4096;

    // Per-wave staging: waves 0,1 copy K frags 0-3 / 4-7; waves 2,3 same for V.
    const _Float16* gsrc = ((wave < 2) ? Kf : Vf) + tb + (wave & 1) * 2048 + lane * 8;
    _Float16* dstA = ((wave < 2) ? &ldsK[0][0] : &ldsV[0][0]) + (wave & 1) * 2048;
    _Float16* dstB = ((wave < 2) ? &ldsK[1][0] : &ldsV[1][0]) + (wave & 1) * 2048;

    #define STAGE(kt_, d_) do {                                          \
        const _Float16* s_ = gsrc + (size_t)(kt_) * 4096;                \
        _Float16* dd_ = (d_);                                            \
        _Pragma("unroll")                                                \
        for (int i_ = 0; i_ < 4; ++i_)                                   \
            async_copy16(s_ + i_ * 512, dd_ + i_ * 512);                 \
    } while (0)

    STAGE(0, dstA);                                  // tile 0 in flight

    // Q fragment (B-operand: n=ln15, k=quad*8+j), scale log2(e)/64 folded
    const float qscale = 1.44269504f / 64.0f;
    half8_t qfrag[2];
    {
        const float* qp = Q + base + (size_t)(qrow + ln15) * DH + quad * 8;
        #pragma unroll
        for (int k0 = 0; k0 < 2; ++k0) {
            float4 a = *(const float4*)(qp + k0 * 32);
            float4 b2 = *(const float4*)(qp + k0 * 32 + 4);
            qfrag[k0] = (half8_t){
                (_Float16)(a.x * qscale), (_Float16)(a.y * qscale),
                (_Float16)(a.z * qscale), (_Float16)(a.w * qscale),
                (_Float16)(b2.x * qscale), (_Float16)(b2.y * qscale),
                (_Float16)(b2.z * qscale), (_Float16)(b2.w * qscale) };
        }
    }

    f32x4 acc[4] = {};                               // O^T accumulator (d-chunks)
    float l_lane = 0.f;                              // lane-partial denom

    // Lane-fixed LDS read bases (all frag reads are base + imm offset)
    const _Float16* kA = &ldsK[0][0] + lane * 8;
    const _Float16* kB = &ldsK[1][0] + lane * 8;
    const _Float16* vA = &ldsV[0][0] + lane * 8;
    const _Float16* vB = &ldsV[1][0] + lane * 8;
    const int myrel = wave * 16 + ln15;              // row within the 64-q block
    const int kq4 = quad * 4;

    __syncthreads();

    for (int kt = 0; kt <= qb; ++kt) {
        const _Float16* kk = (kt & 1) ? kB : kA;
        const _Float16* vv = (kt & 1) ? vB : vA;
        if (kt < qb) STAGE(kt + 1, ((kt + 1) & 1) ? dstB : dstA);

        // ---- S^T = K x Q^T : st[c] has q=ln15, kidx=c*16+quad*4+reg ----
        f32x4 st[4];
        #pragma unroll
        for (int c = 0; c < 4; ++c) {
            half8_t kf0 = *(const half8_t*)(kk + c * 1024);
            half8_t kf1 = *(const half8_t*)(kk + c * 1024 + 512);
            f32x4 a = {};
            a = __builtin_amdgcn_mfma_f32_16x16x32_f16(kf0, qfrag[0], a, 0, 0, 0);
            a = __builtin_amdgcn_mfma_f32_16x16x32_f16(kf1, qfrag[1], a, 0, 0, 0);
            st[c] = a;
        }

        // ---- softmax: register-resident, one q-row per lane ----
        float p[4][4];
        #pragma unroll
        for (int c = 0; c < 4; ++c)
            #pragma unroll
            for (int rr = 0; rr < 4; ++rr)
                p[c][rr] = __builtin_amdgcn_exp2f(st[c][rr]);

        if (kt == qb) {                              // diagonal tile only
            #pragma unroll
            for (int c = 0; c < 4; ++c)
                #pragma unroll
                for (int rr = 0; rr < 4; ++rr)
                    if (c * 16 + kq4 + rr > myrel) p[c][rr] = 0.f;
        }

        // lane-partial row sum (tree); cross-quad reduce deferred to epilogue
        float s0 = (p[0][0] + p[0][1]) + (p[0][2] + p[0][3]);
        float s1 = (p[1][0] + p[1][1]) + (p[1][2] + p[1][3]);
        float s2 = (p[2][0] + p[2][1]) + (p[2][2] + p[2][3]);
        float s3 = (p[3][0] + p[3][1]) + (p[3][2] + p[3][3]);
        l_lane += (s0 + s1) + (s2 + s3);

        // packed P fragments: pb(k1) = concat(pfrag[2k1], pfrag[2k1+1])
        union P8 { half2_t h2[4]; half8_t h8; };
        P8 u0, u1;
        u0.h2[0] = pkrtz(p[0][0], p[0][1]);
        u0.h2[1] = pkrtz(p[0][2], p[0][3]);
        u0.h2[2] = pkrtz(p[1][0], p[1][1]);
        u0.h2[3] = pkrtz(p[1][2], p[1][3]);
        u1.h2[0] = pkrtz(p[2][0], p[2][1]);
        u1.h2[1] = pkrtz(p[2][2], p[2][3]);
        u1.h2[2] = pkrtz(p[3][0], p[3][1]);
        u1.h2[3] = pkrtz(p[3][2], p[3][3]);
        half8_t pb0 = u0.h8, pb1 = u1.h8;

        // ---- O^T += V^T x P^T (16x16x32 f16, permuted-k Vf layout) ----
        #pragma unroll
        for (int cn = 0; cn < 4; ++cn) {
            half8_t vf0 = *(const half8_t*)(vv + cn * 1024);
            acc[cn] = __builtin_amdgcn_mfma_f32_16x16x32_f16(vf0, pb0, acc[cn], 0, 0, 0);
            half8_t vf1 = *(const half8_t*)(vv + cn * 1024 + 512);
            acc[cn] = __builtin_amdgcn_mfma_f32_16x16x32_f16(vf1, pb1, acc[cn], 0, 0, 0);
        }
        __syncthreads();
    }

    // ---- epilogue: lane owns row qrow+ln15, d = cn*16 + quad*4 + reg ----
    {
        float l_i = l_lane + __shfl_xor(l_lane, 16);
        l_i += __shfl_xor(l_i, 32);
        const float rl = 1.0f / l_i;
        float* op = O + base + (size_t)(qrow + ln15) * DH;
        #pragma unroll
        for (int cn = 0; cn < 4; ++cn) {
            float4 o;
            o.x = acc[cn][0] * rl;
            o.y = acc[cn][1] * rl;
            o.z = acc[cn][2] * rl;
            o.w = acc[cn][3] * rl;
            *(float4*)(op + cn * 16 + kq4) = o;
        }
    }
    #undef STAGE
}

extern "C" void kernel_launch(void* const* d_in, const int* in_sizes, int n_in,
                              void* d_out, int out_size, void* d_ws, size_t ws_size,
                              hipStream_t stream) {
    const float* Q = (const float*)d_in[0];
    const float* K = (const float*)d_in[1];
    const float* V = (const float*)d_in[2];
    float* O = (float*)d_out;
    _Float16* Kf = (_Float16*)d_ws;
    _Float16* Vf = Kf + (size_t)NT * 4096;           // 8 MB each
    prep_kv<<<2 * NT, 256, 0, stream>>>(K, V, Kf, Vf);
    fattn_kernel<<<NQB * BHH, 256, 0, stream>>>(Q, Kf, Vf, O);
}